// Round 13
// baseline (8322.176 us; speedup 1.0000x reference)
//
#include <hip/hip_runtime.h>

typedef unsigned short u16;
typedef unsigned long long u64;
typedef __attribute__((ext_vector_type(8))) short short8;
typedef __attribute__((ext_vector_type(4))) float f32x4;

#define HH 1024
#define BB 64
#define TT 512
#define G3 3072
#define NBLK 192
#define NS 513                 // h time-slots (renamed buffers)
#define SLOT (BB * HH)         // elems per h slot
#define FSTRIDE 32             // flag padding: one 128B line per slot
#define RING 32                // xg1 ring depth
#define SENT 0x7FC07FC0u       // 2x bf16 NaN sentinel (finite h never NaN)

__device__ __forceinline__ u16 f2b(float f) {
  unsigned u = __float_as_uint(f);
  unsigned r = (u + 0x7fffu + ((u >> 16) & 1u)) >> 16;
  return (u16)r;
}
__device__ __forceinline__ float b2f(u16 h) {
  return __uint_as_float(((unsigned)h) << 16);
}
__device__ __forceinline__ float ftanh(float x) {
  x = fminf(15.f, fmaxf(-15.f, x));
  float e = __expf(2.f * x);
  return (e - 1.f) / (e + 1.f);
}

__device__ __forceinline__ void st_u32_agent(unsigned* p, unsigned v) {
  __hip_atomic_store(p, v, __ATOMIC_RELAXED, __HIP_MEMORY_SCOPE_AGENT);
}
__device__ __forceinline__ unsigned ld_u32_agent(const unsigned* p) {
  return __hip_atomic_load(p, __ATOMIC_RELAXED, __HIP_MEMORY_SCOPE_AGENT);
}
__device__ __forceinline__ u64 ld_u64_agent(const u64* p) {
  return __hip_atomic_load(p, __ATOMIC_RELAXED, __HIP_MEMORY_SCOPE_AGENT);
}

// sentinel-poll one MFMA A-operand set: 32 short8 (= 64 u64) from a renamed
// hbuf slot. Retry any u64 whose u32 half is still the sentinel. The data
// arrival IS the synchronization (no flags, no barriers, no fences).
union AW { short8 s8; u64 d[2]; unsigned w[4]; };
__device__ __forceinline__ void poll_A(const u16* Ap, AW aw[32]) {
  const u64* p = (const u64*)Ap;
#pragma unroll
  for (int ks = 0; ks < 32; ++ks) {
    aw[ks].d[0] = ld_u64_agent(p + ks * 8);
    aw[ks].d[1] = ld_u64_agent(p + ks * 8 + 1);
  }
  for (;;) {
    int bad = 0;
#pragma unroll
    for (int ks = 0; ks < 32; ++ks) {
      if (aw[ks].w[0] == SENT || aw[ks].w[1] == SENT) {
        aw[ks].d[0] = ld_u64_agent(p + ks * 8); bad = 1;
      }
      if (aw[ks].w[2] == SENT || aw[ks].w[3] == SENT) {
        aw[ks].d[1] = ld_u64_agent(p + ks * 8 + 1); bad = 1;
      }
    }
    if (!bad) break;
  }
}

// ---------------- elementwise converts / init / sentinel fill ----------------

__global__ void f32_to_bf16_k(const float* __restrict__ s, u16* __restrict__ d, int n) {
  int stride = gridDim.x * blockDim.x * 4;
  for (int i = (blockIdx.x * blockDim.x + threadIdx.x) * 4; i < n; i += stride) {
    float4 v = *(const float4*)(s + i);
    uint2 p;
    p.x = (unsigned)f2b(v.x) | ((unsigned)f2b(v.y) << 16);
    p.y = (unsigned)f2b(v.z) | ((unsigned)f2b(v.w) << 16);
    *(uint2*)(d + i) = p;
  }
}

__global__ void fill_sent_k(unsigned* __restrict__ d, int n4) {
  uint4 s = {SENT, SENT, SENT, SENT};
  int stride = gridDim.x * blockDim.x * 4;
  for (int i = (blockIdx.x * blockDim.x + threadIdx.x) * 4; i < n4; i += stride)
    *(uint4*)(d + i) = s;
}

__global__ void init_h_k(const float* __restrict__ h0in, u16* __restrict__ hbuf0,
                         u16* __restrict__ hbuf1) {
  int i = blockIdx.x * blockDim.x + threadIdx.x;
  if (i < BB * HH) {
    hbuf0[i] = f2b(h0in[i]);            // slot 0 = H0(0)
    hbuf1[i] = f2b(h0in[BB * HH + i]);  // slot 0 = H1(0)
  }
}

// ---------------- phase A: xg0 = bf16(x @ W_ih0^T + b_ih0) ----------------

__global__ __launch_bounds__(256) void gemm_xg_k(
    const u16* __restrict__ A, const u16* __restrict__ Wt,
    const float* __restrict__ bias, u16* __restrict__ C) {
  const int bm = blockIdx.x / 24;
  const int bn = blockIdx.x % 24;
  const int m0 = bm * 128, n0 = bn * 128;
  __shared__ __align__(16) u16 al[128 * 40];
  __shared__ __align__(16) u16 bl[128 * 40];
  const int tid = threadIdx.x;
  const int w = tid >> 6, l = tid & 63;
  const int wr = w >> 1, wc = w & 1;
  const int c0 = tid, c1 = tid + 256;
  const int r0 = c0 >> 2, s0 = c0 & 3, r1 = c1 >> 2, s1 = c1 & 3;

  const f32x4 fzero = {0.f, 0.f, 0.f, 0.f};
  f32x4 acc[4][4];
#pragma unroll
  for (int i = 0; i < 4; ++i)
#pragma unroll
    for (int j = 0; j < 4; ++j) acc[i][j] = fzero;

  const u16* a0p = A + (size_t)(m0 + r0) * 1024 + s0 * 8;
  const u16* a1p = A + (size_t)(m0 + r1) * 1024 + s1 * 8;
  const u16* b0p = Wt + (size_t)(n0 + r0) * 1024 + s0 * 8;
  const u16* b1p = Wt + (size_t)(n0 + r1) * 1024 + s1 * 8;

  int4 va0 = *(const int4*)(a0p);
  int4 va1 = *(const int4*)(a1p);
  int4 vb0 = *(const int4*)(b0p);
  int4 vb1 = *(const int4*)(b1p);

  for (int kt = 0; kt < 32; ++kt) {
    __syncthreads();
    *(int4*)&al[r0 * 40 + s0 * 8] = va0;
    *(int4*)&al[r1 * 40 + s1 * 8] = va1;
    *(int4*)&bl[r0 * 40 + s0 * 8] = vb0;
    *(int4*)&bl[r1 * 40 + s1 * 8] = vb1;
    __syncthreads();
    if (kt < 31) {
      va0 = *(const int4*)(a0p + (kt + 1) * 32);
      va1 = *(const int4*)(a1p + (kt + 1) * 32);
      vb0 = *(const int4*)(b0p + (kt + 1) * 32);
      vb1 = *(const int4*)(b1p + (kt + 1) * 32);
    }
    short8 af[4], bf[4];
#pragma unroll
    for (int i = 0; i < 4; ++i)
      af[i] = *(const short8*)&al[(wr * 64 + i * 16 + (l & 15)) * 40 + (l >> 4) * 8];
#pragma unroll
    for (int j = 0; j < 4; ++j)
      bf[j] = *(const short8*)&bl[(wc * 64 + j * 16 + (l & 15)) * 40 + (l >> 4) * 8];
#pragma unroll
    for (int i = 0; i < 4; ++i)
#pragma unroll
      for (int j = 0; j < 4; ++j)
        acc[i][j] = __builtin_amdgcn_mfma_f32_16x16x32_bf16(af[i], bf[j], acc[i][j], 0, 0, 0);
  }

#pragma unroll
  for (int i = 0; i < 4; ++i) {
#pragma unroll
    for (int j = 0; j < 4; ++j) {
      int col = n0 + wc * 64 + j * 16 + (l & 15);
      float bv = bias[col];
#pragma unroll
      for (int q = 0; q < 4; ++q) {
        int row = m0 + wr * 64 + i * 16 + (l >> 4) * 4 + q;
        C[(size_t)row * G3 + col] = f2b(acc[i][j][q] + bv);
      }
    }
  }
}

// ---------------- persistent fused scan, v12: sentinel dataflow ----------------
// hbuf slots are renamed and pre-filled with NaN sentinels; consumers poll the
// operand data itself (poll_A). Consumer wave w only needs producer wave w's
// rows -> 12 independent wave pipelines, NO barriers/fences/flags on the h
// chains. Ring (reused slots) keeps per-wave flags: flags1[sub*4+w] posted by
// p1 after vmcnt(0); flags2 posted by p2 after gates (vmcnt free there).
//  p0 (blk 0..63):   layer0, t=0..511: poll hbuf0[t], write hbuf0[t+1].
//  p1 (blk 64..127): xg1,    t=1..512: poll hbuf0[t], write ring[t&31], flags1.
//  p2 (blk 128..191):layer1, t=1..512: flags1>=t, ring loads, poll hbuf1[t-1],
//      write hbuf1[t], flags2 (ring slot consumed).

__global__ __launch_bounds__(256, 1) void gru_scan12_k(
    const u16* __restrict__ xg0,
    const u16* __restrict__ whh0, const u16* __restrict__ wih1,
    const u16* __restrict__ whh1,
    const float* __restrict__ bhh0, const float* __restrict__ bih1,
    const float* __restrict__ bhh1,
    const float* __restrict__ h0in,
    u16* __restrict__ hbuf0, u16* __restrict__ hbuf1,
    u16* __restrict__ xg1ring, float* __restrict__ out,
    unsigned* __restrict__ flags1, unsigned* __restrict__ flags2) {
  const int blk = blockIdx.x;
  const int grp = blk >> 6;          // 0,1,2
  const int sub = blk & 63;
  const int tid = threadIdx.x;
  const int w = tid >> 6, l = tid & 63;
  const int lrow = l & 15;
  const int kb = (l >> 4) * 8;
  const int myrow0 = w * 16 + (l >> 4) * 4;
  const size_t arow = (size_t)(w * 16 + lrow) * HH + kb;
  const f32x4 fzero = {0.f, 0.f, 0.f, 0.f};

  __shared__ __align__(16) u16 wlds[48 * 1024];
  {
    const u16* Wsrc = (grp == 0) ? whh0 : (grp == 1) ? wih1 : whh1;
    for (int i = tid; i < 6144; i += 256) {
      int r = i >> 7;
      int c = i & 127;
      int g = r >> 4;
      int wrow = g * HH + sub * 16 + (r & 15);
      int4 v = *(const int4*)(Wsrc + (size_t)wrow * 1024 + c * 8);
      int idx = r * 1024 + ((c * 8) ^ ((r & 7) << 3));
      *(int4*)&wlds[idx] = v;
    }
  }
  __syncthreads();  // LDS W ready; read-only afterwards (waves free-run)

  const int j = sub * 16 + lrow;
  const int sx = (lrow & 7) << 3;
  const int fidx = (sub * 4 + w) * FSTRIDE;  // per-wave flag slot

  if (grp == 0) {
    const float bhr = bhh0[j], bhz = bhh0[HH + j], bhn = bhh0[2 * HH + j];
    float hreg[4];
#pragma unroll
    for (int q = 0; q < 4; ++q) hreg[q] = h0in[(myrow0 + q) * HH + j];

    for (int t = 0; t < TT; ++t) {
      // xg0 prefetch (normal cached loads; complete during the data-poll)
      u16 xrv[4], xzv[4], xnv[4];
      const u16* xp = xg0 + (size_t)t * BB * G3;
#pragma unroll
      for (int q = 0; q < 4; ++q) {
        const u16* rp = xp + (size_t)(myrow0 + q) * G3;
        xrv[q] = rp[j]; xzv[q] = rp[HH + j]; xnv[q] = rp[2 * HH + j];
      }

      AW aw[32];
      poll_A(hbuf0 + (size_t)t * SLOT + arow, aw);

      f32x4 acc0 = fzero, acc1 = fzero, acc2 = fzero;
#pragma unroll
      for (int ks = 0; ks < 32; ++ks) {
        int ke = kb + ks * 32;
        short8 b0 = *(const short8*)&wlds[(lrow) * 1024 + (ke ^ sx)];
        short8 b1 = *(const short8*)&wlds[(16 + lrow) * 1024 + (ke ^ sx)];
        short8 b2 = *(const short8*)&wlds[(32 + lrow) * 1024 + (ke ^ sx)];
        acc0 = __builtin_amdgcn_mfma_f32_16x16x32_bf16(aw[ks].s8, b0, acc0, 0, 0, 0);
        acc1 = __builtin_amdgcn_mfma_f32_16x16x32_bf16(aw[ks].s8, b1, acc1, 0, 0, 0);
        acc2 = __builtin_amdgcn_mfma_f32_16x16x32_bf16(aw[ks].s8, b2, acc2, 0, 0, 0);
      }

      u16* hbn = hbuf0 + (size_t)(t + 1) * SLOT;
#pragma unroll
      for (int q = 0; q < 4; ++q) {
        float rr = acc0[q] + bhr + b2f(xrv[q]);
        float zz = acc1[q] + bhz + b2f(xzv[q]);
        float nn = acc2[q] + bhn;
        float r = 1.f / (1.f + __expf(-rr));
        float z = 1.f / (1.f + __expf(-zz));
        float n = ftanh(b2f(xnv[q]) + r * nn);
        float hv = (1.f - z) * n + z * hreg[q];
        hreg[q] = hv;
        int hb = (int)f2b(hv);
        int nb = __shfl_xor(hb, 1);
        if ((l & 1) == 0) {
          unsigned pk = (unsigned)(u16)hb | (((unsigned)(u16)nb) << 16);
          st_u32_agent((unsigned*)(hbn + (size_t)(myrow0 + q) * HH + j), pk);
        }
      }
      // no drain, no flag: consumers sentinel-poll the stores themselves
    }
#pragma unroll
    for (int q = 0; q < 4; ++q) out[(size_t)(myrow0 + q) * HH + j] = hreg[q];

  } else if (grp == 1) {
    const float bir = bih1[j], biz = bih1[HH + j], bin = bih1[2 * HH + j];

    for (int t = 1; t <= TT; ++t) {
      // ring back-pressure (pre-satisfied with RING=32 slack)
      for (;;) {
        unsigned f = ld_u32_agent(&flags2[fidx]);
        if ((int)f >= t - RING) break;
      }
      __builtin_amdgcn_fence(__ATOMIC_ACQUIRE, "workgroup");  // compiler order

      AW aw[32];
      poll_A(hbuf0 + (size_t)t * SLOT + arow, aw);

      f32x4 acc0 = fzero, acc1 = fzero, acc2 = fzero;
#pragma unroll
      for (int ks = 0; ks < 32; ++ks) {
        int ke = kb + ks * 32;
        short8 b0 = *(const short8*)&wlds[(lrow) * 1024 + (ke ^ sx)];
        short8 b1 = *(const short8*)&wlds[(16 + lrow) * 1024 + (ke ^ sx)];
        short8 b2 = *(const short8*)&wlds[(32 + lrow) * 1024 + (ke ^ sx)];
        acc0 = __builtin_amdgcn_mfma_f32_16x16x32_bf16(aw[ks].s8, b0, acc0, 0, 0, 0);
        acc1 = __builtin_amdgcn_mfma_f32_16x16x32_bf16(aw[ks].s8, b1, acc1, 0, 0, 0);
        acc2 = __builtin_amdgcn_mfma_f32_16x16x32_bf16(aw[ks].s8, b2, acc2, 0, 0, 0);
      }

      // packed bf16 ring write (even lanes)
      u16* ox = xg1ring + (size_t)(t & (RING - 1)) * (BB * G3);
#pragma unroll
      for (int q = 0; q < 4; ++q) {
        int row = myrow0 + q;
        int a0v = (int)f2b(acc0[q] + bir); int a0n = __shfl_xor(a0v, 1);
        int a1v = (int)f2b(acc1[q] + biz); int a1n = __shfl_xor(a1v, 1);
        int a2v = (int)f2b(acc2[q] + bin); int a2n = __shfl_xor(a2v, 1);
        if ((l & 1) == 0) {
          st_u32_agent((unsigned*)(ox + (size_t)row * G3 + j),
                       (unsigned)(u16)a0v | (((unsigned)(u16)a0n) << 16));
          st_u32_agent((unsigned*)(ox + (size_t)row * G3 + HH + j),
                       (unsigned)(u16)a1v | (((unsigned)(u16)a1n) << 16));
          st_u32_agent((unsigned*)(ox + (size_t)row * G3 + 2 * HH + j),
                       (unsigned)(u16)a2v | (((unsigned)(u16)a2n) << 16));
        }
      }
      // wave-wide drain of the ring stores, then per-wave flag
      asm volatile("s_waitcnt vmcnt(0)" ::: "memory");
      if (l == 0) st_u32_agent(&flags1[fidx], (unsigned)t);
    }

  } else {
    const float bhr = bhh1[j], bhz = bhh1[HH + j], bhn = bhh1[2 * HH + j];
    float hreg[4];
#pragma unroll
    for (int q = 0; q < 4; ++q) hreg[q] = h0in[BB * HH + (myrow0 + q) * HH + j];
    const int jpair = j & ~1;
    const int sel = (j & 1) * 16;

    for (int t = 1; t <= TT; ++t) {
      // wait own column-slice producer wave (usually pre-satisfied)
      for (;;) {
        unsigned f = ld_u32_agent(&flags1[fidx]);
        if (f >= (unsigned)t) break;
      }
      __builtin_amdgcn_fence(__ATOMIC_ACQUIRE, "workgroup");  // compiler order

      // ring loads (valid per flags1), then A-poll spins while they fly
      const u16* ox = xg1ring + (size_t)(t & (RING - 1)) * (BB * G3);
      unsigned pr[4], pz[4], pn[4];
#pragma unroll
      for (int q = 0; q < 4; ++q) {
        const u16* rp = ox + (size_t)(myrow0 + q) * G3;
        pr[q] = ld_u32_agent((const unsigned*)(rp + jpair));
        pz[q] = ld_u32_agent((const unsigned*)(rp + HH + jpair));
        pn[q] = ld_u32_agent((const unsigned*)(rp + 2 * HH + jpair));
      }

      AW aw[32];
      poll_A(hbuf1 + (size_t)(t - 1) * SLOT + arow, aw);

      f32x4 acc0 = fzero, acc1 = fzero, acc2 = fzero;
#pragma unroll
      for (int ks = 0; ks < 32; ++ks) {
        int ke = kb + ks * 32;
        short8 b0 = *(const short8*)&wlds[(lrow) * 1024 + (ke ^ sx)];
        short8 b1 = *(const short8*)&wlds[(16 + lrow) * 1024 + (ke ^ sx)];
        short8 b2 = *(const short8*)&wlds[(32 + lrow) * 1024 + (ke ^ sx)];
        acc0 = __builtin_amdgcn_mfma_f32_16x16x32_bf16(aw[ks].s8, b0, acc0, 0, 0, 0);
        acc1 = __builtin_amdgcn_mfma_f32_16x16x32_bf16(aw[ks].s8, b1, acc1, 0, 0, 0);
        acc2 = __builtin_amdgcn_mfma_f32_16x16x32_bf16(aw[ks].s8, b2, acc2, 0, 0, 0);
      }

      float hv4[4];
#pragma unroll
      for (int q = 0; q < 4; ++q) {
        float rr = acc0[q] + bhr + b2f((u16)(pr[q] >> sel));
        float zz = acc1[q] + bhz + b2f((u16)(pz[q] >> sel));
        float nn = acc2[q] + bhn;
        float r = 1.f / (1.f + __expf(-rr));
        float z = 1.f / (1.f + __expf(-zz));
        float n = ftanh(b2f((u16)(pn[q] >> sel)) + r * nn);
        hv4[q] = (1.f - z) * n + z * hreg[q];
        hreg[q] = hv4[q];
      }
      // all loads consumed above -> vmcnt(0) is ~free; post ring-consumed flag
      asm volatile("s_waitcnt vmcnt(0)" ::: "memory");
      if (l == 0) st_u32_agent(&flags2[fidx], (unsigned)t);

      u16* hbn = hbuf1 + (size_t)t * SLOT;
#pragma unroll
      for (int q = 0; q < 4; ++q) {
        int hb = (int)f2b(hv4[q]);
        int nb = __shfl_xor(hb, 1);
        if ((l & 1) == 0) {
          unsigned pk = (unsigned)(u16)hb | (((unsigned)(u16)nb) << 16);
          st_u32_agent((unsigned*)(hbn + (size_t)(myrow0 + q) * HH + j), pk);
        }
      }
    }
#pragma unroll
    for (int q = 0; q < 4; ++q) out[BB * HH + (size_t)(myrow0 + q) * HH + j] = hreg[q];
  }
}

// ---------------- host ----------------

extern "C" void kernel_launch(void* const* d_in, const int* in_sizes, int n_in,
                              void* d_out, int out_size, void* d_ws, size_t ws_size,
                              hipStream_t stream) {
  const float* x   = (const float*)d_in[0];
  const float* h0  = (const float*)d_in[1];
  const float* wih = (const float*)d_in[2];
  const float* whh = (const float*)d_in[3];
  const float* bih = (const float*)d_in[4];
  const float* bhh = (const float*)d_in[5];
  float* out = (float*)d_out;

  char* ws = (char*)d_ws;
  size_t off = 0;
  auto alloc = [&](size_t bytes) -> void* {
    void* p = ws + off;
    off += (bytes + 255) & ~(size_t)255;
    return p;
  };
  u16* xg0   = (u16*)alloc((size_t)TT * BB * G3 * 2);        // 193 MB
  u16* wihb  = (u16*)alloc((size_t)2 * G3 * HH * 2);         // 12.6 MB
  u16* whhb  = (u16*)alloc((size_t)2 * G3 * HH * 2);         // 12.6 MB
  // union: xbf (64 MB, dead after gemm) overlaid by hbuf0/hbuf1 (134.5 MB)
  size_t hbytes = (size_t)2 * NS * SLOT * 2;
  size_t xbytes = (size_t)TT * BB * HH * 2;
  char* un = (char*)alloc(hbytes > xbytes ? hbytes : xbytes);
  u16* xbf   = (u16*)un;
  u16* hbuf0 = (u16*)un;
  u16* hbuf1 = hbuf0 + (size_t)NS * SLOT;
  u16* xg1ring = (u16*)alloc((size_t)RING * BB * G3 * 2);    // 12.6 MB (bf16)
  unsigned* flags1 = (unsigned*)alloc(256 * FSTRIDE * 4);
  unsigned* flags2 = (unsigned*)alloc(256 * FSTRIDE * 4);

  hipMemsetAsync(flags1, 0, 256 * FSTRIDE * 4, stream);
  hipMemsetAsync(flags2, 0, 256 * FSTRIDE * 4, stream);
  f32_to_bf16_k<<<2048, 256, 0, stream>>>(x, xbf, TT * BB * HH);
  f32_to_bf16_k<<<512, 256, 0, stream>>>(wih, wihb, 2 * G3 * HH);
  f32_to_bf16_k<<<512, 256, 0, stream>>>(whh, whhb, 2 * G3 * HH);

  gemm_xg_k<<<6144, 256, 0, stream>>>(xbf, wihb, bih, xg0);

  // after gemm (hbuf aliases xbf): sentinel-fill ALL slots, then real h0 slot
  fill_sent_k<<<4096, 256, 0, stream>>>((unsigned*)hbuf0, NS * SLOT);
  init_h_k<<<256, 256, 0, stream>>>(h0, hbuf0, hbuf1);

  gru_scan12_k<<<NBLK, 256, 0, stream>>>(xg0,
                                         whhb, wihb + (size_t)G3 * HH, whhb + (size_t)G3 * HH,
                                         bhh, bih + G3, bhh + G3, h0,
                                         hbuf0, hbuf1, xg1ring, out, flags1, flags2);
}

// Round 14
// 5391.233 us; speedup vs baseline: 1.5436x; 1.5436x over previous
//
#include <hip/hip_runtime.h>

typedef unsigned short u16;
typedef unsigned long long u64;
typedef __attribute__((ext_vector_type(8))) short short8;
typedef __attribute__((ext_vector_type(4))) float f32x4;

#define HH 1024
#define BB 64
#define TT 512
#define G3 3072
#define NBLK 192
#define NS 513                 // h time-slots (renamed buffers)
#define SLOT (BB * HH)         // elems per h slot
#define FSTRIDE 32             // flag padding: one 128B line per wave-slot
#define RING 32                // xg1 ring depth

__device__ __forceinline__ u16 f2b(float f) {
  unsigned u = __float_as_uint(f);
  unsigned r = (u + 0x7fffu + ((u >> 16) & 1u)) >> 16;
  return (u16)r;
}
__device__ __forceinline__ float b2f(u16 h) {
  return __uint_as_float(((unsigned)h) << 16);
}
__device__ __forceinline__ float ftanh(float x) {
  x = fminf(15.f, fmaxf(-15.f, x));
  float e = __expf(2.f * x);
  return (e - 1.f) / (e + 1.f);
}

__device__ __forceinline__ void st_u32_agent(unsigned* p, unsigned v) {
  __hip_atomic_store(p, v, __ATOMIC_RELAXED, __HIP_MEMORY_SCOPE_AGENT);
}
__device__ __forceinline__ unsigned ld_u32_agent(const unsigned* p) {
  return __hip_atomic_load(p, __ATOMIC_RELAXED, __HIP_MEMORY_SCOPE_AGENT);
}

// ---------------- elementwise converts / init ----------------

__global__ void f32_to_bf16_k(const float* __restrict__ s, u16* __restrict__ d, int n) {
  int stride = gridDim.x * blockDim.x * 4;
  for (int i = (blockIdx.x * blockDim.x + threadIdx.x) * 4; i < n; i += stride) {
    float4 v = *(const float4*)(s + i);
    uint2 p;
    p.x = (unsigned)f2b(v.x) | ((unsigned)f2b(v.y) << 16);
    p.y = (unsigned)f2b(v.z) | ((unsigned)f2b(v.w) << 16);
    *(uint2*)(d + i) = p;
  }
}

__global__ void init_h_k(const float* __restrict__ h0in, u16* __restrict__ hbuf0,
                         u16* __restrict__ hbuf1) {
  int i = blockIdx.x * blockDim.x + threadIdx.x;
  if (i < BB * HH) {
    hbuf0[i] = f2b(h0in[i]);            // slot 0 = H0(0)
    hbuf1[i] = f2b(h0in[BB * HH + i]);  // slot 0 = H1(0)
  }
}

// ---------------- phase A: xg0 = bf16(x @ W_ih0^T + b_ih0) ----------------

__global__ __launch_bounds__(256) void gemm_xg_k(
    const u16* __restrict__ A, const u16* __restrict__ Wt,
    const float* __restrict__ bias, u16* __restrict__ C) {
  const int bm = blockIdx.x / 24;
  const int bn = blockIdx.x % 24;
  const int m0 = bm * 128, n0 = bn * 128;
  __shared__ __align__(16) u16 al[128 * 40];
  __shared__ __align__(16) u16 bl[128 * 40];
  const int tid = threadIdx.x;
  const int w = tid >> 6, l = tid & 63;
  const int wr = w >> 1, wc = w & 1;
  const int c0 = tid, c1 = tid + 256;
  const int r0 = c0 >> 2, s0 = c0 & 3, r1 = c1 >> 2, s1 = c1 & 3;

  const f32x4 fzero = {0.f, 0.f, 0.f, 0.f};
  f32x4 acc[4][4];
#pragma unroll
  for (int i = 0; i < 4; ++i)
#pragma unroll
    for (int j = 0; j < 4; ++j) acc[i][j] = fzero;

  const u16* a0p = A + (size_t)(m0 + r0) * 1024 + s0 * 8;
  const u16* a1p = A + (size_t)(m0 + r1) * 1024 + s1 * 8;
  const u16* b0p = Wt + (size_t)(n0 + r0) * 1024 + s0 * 8;
  const u16* b1p = Wt + (size_t)(n0 + r1) * 1024 + s1 * 8;

  int4 va0 = *(const int4*)(a0p);
  int4 va1 = *(const int4*)(a1p);
  int4 vb0 = *(const int4*)(b0p);
  int4 vb1 = *(const int4*)(b1p);

  for (int kt = 0; kt < 32; ++kt) {
    __syncthreads();
    *(int4*)&al[r0 * 40 + s0 * 8] = va0;
    *(int4*)&al[r1 * 40 + s1 * 8] = va1;
    *(int4*)&bl[r0 * 40 + s0 * 8] = vb0;
    *(int4*)&bl[r1 * 40 + s1 * 8] = vb1;
    __syncthreads();
    if (kt < 31) {
      va0 = *(const int4*)(a0p + (kt + 1) * 32);
      va1 = *(const int4*)(a1p + (kt + 1) * 32);
      vb0 = *(const int4*)(b0p + (kt + 1) * 32);
      vb1 = *(const int4*)(b1p + (kt + 1) * 32);
    }
    short8 af[4], bf[4];
#pragma unroll
    for (int i = 0; i < 4; ++i)
      af[i] = *(const short8*)&al[(wr * 64 + i * 16 + (l & 15)) * 40 + (l >> 4) * 8];
#pragma unroll
    for (int j = 0; j < 4; ++j)
      bf[j] = *(const short8*)&bl[(wc * 64 + j * 16 + (l & 15)) * 40 + (l >> 4) * 8];
#pragma unroll
    for (int i = 0; i < 4; ++i)
#pragma unroll
      for (int j = 0; j < 4; ++j)
        acc[i][j] = __builtin_amdgcn_mfma_f32_16x16x32_bf16(af[i], bf[j], acc[i][j], 0, 0, 0);
  }

#pragma unroll
  for (int i = 0; i < 4; ++i) {
#pragma unroll
    for (int j = 0; j < 4; ++j) {
      int col = n0 + wc * 64 + j * 16 + (l & 15);
      float bv = bias[col];
#pragma unroll
      for (int q = 0; q < 4; ++q) {
        int row = m0 + wr * 64 + i * 16 + (l >> 4) * 4 + q;
        C[(size_t)row * G3 + col] = f2b(acc[i][j][q] + bv);
      }
    }
  }
}

// ---------------- persistent fused scan, v13: per-WAVE pipelines ----------------
// R12 structure (flags + cached renamed h reads, proven 8 us/step) with the
// block-level coupling removed: dataflow is wave-aligned (wave w of every
// block produces/consumes rows w*16..+15), so flags are per-wave, drains are
// per-wave s_waitcnt, and there are NO __syncthreads in the t-loops ->
// 768 independent wave pipelines.
//  p0 (blk 0..63):   layer0, t=0..511: poll flags0[*,w]>=t, read hbuf0[t]
//      (cached), write hbuf0[t+1] (sc1), drain, post flags0[sub,w]=t+1.
//  p1 (blk 64..127): xg1, t=1..512: poll flags0[*,w]>=t + ring backpressure
//      flags2[sub,w]>=t-RING; write ring[t&31] (sc1); post flags1[sub,w]=t.
//  p2 (blk 128..191):layer1, t=1..512: poll flags1[sub,w]>=t +
//      flags2[*,w]>=t-1; read hbuf1[t-1] (cached) + ring (sc1);
//      write hbuf1[t]; drain; post flags2[sub,w]=t.

__global__ __launch_bounds__(256, 1) void gru_scan13_k(
    const u16* __restrict__ xg0,
    const u16* __restrict__ whh0, const u16* __restrict__ wih1,
    const u16* __restrict__ whh1,
    const float* __restrict__ bhh0, const float* __restrict__ bih1,
    const float* __restrict__ bhh1,
    const float* __restrict__ h0in,
    u16* __restrict__ hbuf0, u16* __restrict__ hbuf1,
    u16* __restrict__ xg1ring, float* __restrict__ out,
    unsigned* __restrict__ flags0, unsigned* __restrict__ flags1,
    unsigned* __restrict__ flags2) {
  const int blk = blockIdx.x;
  const int grp = blk >> 6;          // 0,1,2
  const int sub = blk & 63;
  const int tid = threadIdx.x;
  const int w = tid >> 6, l = tid & 63;
  const int lrow = l & 15;
  const int kb = (l >> 4) * 8;
  const int myrow0 = w * 16 + (l >> 4) * 4;
  const size_t arow = (size_t)(w * 16 + lrow) * HH + kb;
  const f32x4 fzero = {0.f, 0.f, 0.f, 0.f};

  __shared__ __align__(16) u16 wlds[48 * 1024];
  {
    const u16* Wsrc = (grp == 0) ? whh0 : (grp == 1) ? wih1 : whh1;
    for (int i = tid; i < 6144; i += 256) {
      int r = i >> 7;
      int c = i & 127;
      int g = r >> 4;
      int wrow = g * HH + sub * 16 + (r & 15);
      int4 v = *(const int4*)(Wsrc + (size_t)wrow * 1024 + c * 8);
      int idx = r * 1024 + ((c * 8) ^ ((r & 7) << 3));
      *(int4*)&wlds[idx] = v;
    }
  }
  __syncthreads();  // wlds ready; read-only afterwards -> waves free-run
  // one-time cross-replay staleness guard (kills stale L1/L2 lines from the
  // previous graph replay; within a launch every renamed line is read fresh)
  __builtin_amdgcn_fence(__ATOMIC_ACQUIRE, "agent");

  const int j = sub * 16 + lrow;
  const int sx = (lrow & 7) << 3;
  const int myf = (sub * 4 + w) * FSTRIDE;   // this wave's flag slot
  const int plf = (l * 4 + w) * FSTRIDE;     // producer-block l, wave w

  if (grp == 0) {
    const float bhr = bhh0[j], bhz = bhh0[HH + j], bhn = bhh0[2 * HH + j];
    float hreg[4];
#pragma unroll
    for (int q = 0; q < 4; ++q) hreg[q] = h0in[(myrow0 + q) * HH + j];

    for (int t = 0; t < TT; ++t) {
      // xg0 prefetch (cached; completes under the poll)
      u16 xrv[4], xzv[4], xnv[4];
      const u16* xp = xg0 + (size_t)t * BB * G3;
#pragma unroll
      for (int q = 0; q < 4; ++q) {
        const u16* rp = xp + (size_t)(myrow0 + q) * G3;
        xrv[q] = rp[j]; xzv[q] = rp[HH + j]; xnv[q] = rp[2 * HH + j];
      }
      if (t > 0) {
        for (;;) {
          unsigned a0 = ld_u32_agent(&flags0[plf]);
          if (__all(a0 >= (unsigned)t)) break;
        }
      }
      __builtin_amdgcn_fence(__ATOMIC_ACQUIRE, "workgroup");  // compiler order

      const u16* Ap = hbuf0 + (size_t)t * SLOT + arow;
      short8 ar[32];
#pragma unroll
      for (int ks = 0; ks < 32; ++ks) ar[ks] = *(const short8*)(Ap + ks * 32);

      f32x4 acc0 = fzero, acc1 = fzero, acc2 = fzero;
#pragma unroll
      for (int ks = 0; ks < 32; ++ks) {
        int ke = kb + ks * 32;
        short8 b0 = *(const short8*)&wlds[(lrow) * 1024 + (ke ^ sx)];
        short8 b1 = *(const short8*)&wlds[(16 + lrow) * 1024 + (ke ^ sx)];
        short8 b2 = *(const short8*)&wlds[(32 + lrow) * 1024 + (ke ^ sx)];
        acc0 = __builtin_amdgcn_mfma_f32_16x16x32_bf16(ar[ks], b0, acc0, 0, 0, 0);
        acc1 = __builtin_amdgcn_mfma_f32_16x16x32_bf16(ar[ks], b1, acc1, 0, 0, 0);
        acc2 = __builtin_amdgcn_mfma_f32_16x16x32_bf16(ar[ks], b2, acc2, 0, 0, 0);
      }

      u16* hbn = hbuf0 + (size_t)(t + 1) * SLOT;
#pragma unroll
      for (int q = 0; q < 4; ++q) {
        float rr = acc0[q] + bhr + b2f(xrv[q]);
        float zz = acc1[q] + bhz + b2f(xzv[q]);
        float nn = acc2[q] + bhn;
        float r = 1.f / (1.f + __expf(-rr));
        float z = 1.f / (1.f + __expf(-zz));
        float n = ftanh(b2f(xnv[q]) + r * nn);
        float hv = (1.f - z) * n + z * hreg[q];
        hreg[q] = hv;
        int hb = (int)f2b(hv);
        int nb = __shfl_xor(hb, 1);
        if ((l & 1) == 0) {
          unsigned pk = (unsigned)(u16)hb | (((unsigned)(u16)nb) << 16);
          st_u32_agent((unsigned*)(hbn + (size_t)(myrow0 + q) * HH + j), pk);
        }
      }
      asm volatile("s_waitcnt vmcnt(0)" ::: "memory");  // per-wave drain
      if (l == 0) st_u32_agent(&flags0[myf], (unsigned)(t + 1));
    }
#pragma unroll
    for (int q = 0; q < 4; ++q) out[(size_t)(myrow0 + q) * HH + j] = hreg[q];

  } else if (grp == 1) {
    const float bir = bih1[j], biz = bih1[HH + j], bin = bih1[2 * HH + j];

    for (int t = 1; t <= TT; ++t) {
      for (;;) {
        unsigned a0 = ld_u32_agent(&flags0[plf]);
        unsigned f2 = ld_u32_agent(&flags2[myf]);
        int ok = (a0 >= (unsigned)t) && ((int)f2 >= t - RING);
        if (__all(ok)) break;
      }
      __builtin_amdgcn_fence(__ATOMIC_ACQUIRE, "workgroup");

      const u16* Ap = hbuf0 + (size_t)t * SLOT + arow;
      short8 ar[32];
#pragma unroll
      for (int ks = 0; ks < 32; ++ks) ar[ks] = *(const short8*)(Ap + ks * 32);

      f32x4 acc0 = fzero, acc1 = fzero, acc2 = fzero;
#pragma unroll
      for (int ks = 0; ks < 32; ++ks) {
        int ke = kb + ks * 32;
        short8 b0 = *(const short8*)&wlds[(lrow) * 1024 + (ke ^ sx)];
        short8 b1 = *(const short8*)&wlds[(16 + lrow) * 1024 + (ke ^ sx)];
        short8 b2 = *(const short8*)&wlds[(32 + lrow) * 1024 + (ke ^ sx)];
        acc0 = __builtin_amdgcn_mfma_f32_16x16x32_bf16(ar[ks], b0, acc0, 0, 0, 0);
        acc1 = __builtin_amdgcn_mfma_f32_16x16x32_bf16(ar[ks], b1, acc1, 0, 0, 0);
        acc2 = __builtin_amdgcn_mfma_f32_16x16x32_bf16(ar[ks], b2, acc2, 0, 0, 0);
      }

      u16* ox = xg1ring + (size_t)(t & (RING - 1)) * (BB * G3);
#pragma unroll
      for (int q = 0; q < 4; ++q) {
        int row = myrow0 + q;
        int a0v = (int)f2b(acc0[q] + bir); int a0n = __shfl_xor(a0v, 1);
        int a1v = (int)f2b(acc1[q] + biz); int a1n = __shfl_xor(a1v, 1);
        int a2v = (int)f2b(acc2[q] + bin); int a2n = __shfl_xor(a2v, 1);
        if ((l & 1) == 0) {
          st_u32_agent((unsigned*)(ox + (size_t)row * G3 + j),
                       (unsigned)(u16)a0v | (((unsigned)(u16)a0n) << 16));
          st_u32_agent((unsigned*)(ox + (size_t)row * G3 + HH + j),
                       (unsigned)(u16)a1v | (((unsigned)(u16)a1n) << 16));
          st_u32_agent((unsigned*)(ox + (size_t)row * G3 + 2 * HH + j),
                       (unsigned)(u16)a2v | (((unsigned)(u16)a2n) << 16));
        }
      }
      asm volatile("s_waitcnt vmcnt(0)" ::: "memory");
      if (l == 0) st_u32_agent(&flags1[myf], (unsigned)t);
    }

  } else {
    const float bhr = bhh1[j], bhz = bhh1[HH + j], bhn = bhh1[2 * HH + j];
    float hreg[4];
#pragma unroll
    for (int q = 0; q < 4; ++q) hreg[q] = h0in[BB * HH + (myrow0 + q) * HH + j];
    const int jpair = j & ~1;
    const int sel = (j & 1) * 16;

    for (int t = 1; t <= TT; ++t) {
      for (;;) {
        unsigned f1 = ld_u32_agent(&flags1[myf]);
        unsigned a2 = ld_u32_agent(&flags2[plf]);
        int ok = (f1 >= (unsigned)t) && (a2 >= (unsigned)(t - 1));
        if (__all(ok)) break;
      }
      __builtin_amdgcn_fence(__ATOMIC_ACQUIRE, "workgroup");

      // ring loads (sc1, reused slots) + A loads (cached, renamed)
      const u16* ox = xg1ring + (size_t)(t & (RING - 1)) * (BB * G3);
      unsigned pr[4], pz[4], pn[4];
#pragma unroll
      for (int q = 0; q < 4; ++q) {
        const u16* rp = ox + (size_t)(myrow0 + q) * G3;
        pr[q] = ld_u32_agent((const unsigned*)(rp + jpair));
        pz[q] = ld_u32_agent((const unsigned*)(rp + HH + jpair));
        pn[q] = ld_u32_agent((const unsigned*)(rp + 2 * HH + jpair));
      }
      const u16* Ap = hbuf1 + (size_t)(t - 1) * SLOT + arow;
      short8 ar[32];
#pragma unroll
      for (int ks = 0; ks < 32; ++ks) ar[ks] = *(const short8*)(Ap + ks * 32);

      f32x4 acc0 = fzero, acc1 = fzero, acc2 = fzero;
#pragma unroll
      for (int ks = 0; ks < 32; ++ks) {
        int ke = kb + ks * 32;
        short8 b0 = *(const short8*)&wlds[(lrow) * 1024 + (ke ^ sx)];
        short8 b1 = *(const short8*)&wlds[(16 + lrow) * 1024 + (ke ^ sx)];
        short8 b2 = *(const short8*)&wlds[(32 + lrow) * 1024 + (ke ^ sx)];
        acc0 = __builtin_amdgcn_mfma_f32_16x16x32_bf16(ar[ks], b0, acc0, 0, 0, 0);
        acc1 = __builtin_amdgcn_mfma_f32_16x16x32_bf16(ar[ks], b1, acc1, 0, 0, 0);
        acc2 = __builtin_amdgcn_mfma_f32_16x16x32_bf16(ar[ks], b2, acc2, 0, 0, 0);
      }

      u16* hbn = hbuf1 + (size_t)t * SLOT;
#pragma unroll
      for (int q = 0; q < 4; ++q) {
        float rr = acc0[q] + bhr + b2f((u16)(pr[q] >> sel));
        float zz = acc1[q] + bhz + b2f((u16)(pz[q] >> sel));
        float nn = acc2[q] + bhn;
        float r = 1.f / (1.f + __expf(-rr));
        float z = 1.f / (1.f + __expf(-zz));
        float n = ftanh(b2f((u16)(pn[q] >> sel)) + r * nn);
        float hv = (1.f - z) * n + z * hreg[q];
        hreg[q] = hv;
        int hb = (int)f2b(hv);
        int nb = __shfl_xor(hb, 1);
        if ((l & 1) == 0) {
          unsigned pk = (unsigned)(u16)hb | (((unsigned)(u16)nb) << 16);
          st_u32_agent((unsigned*)(hbn + (size_t)(myrow0 + q) * HH + j), pk);
        }
      }
      asm volatile("s_waitcnt vmcnt(0)" ::: "memory");
      if (l == 0) st_u32_agent(&flags2[myf], (unsigned)t);
    }
#pragma unroll
    for (int q = 0; q < 4; ++q) out[BB * HH + (size_t)(myrow0 + q) * HH + j] = hreg[q];
  }
}

// ---------------- host ----------------

extern "C" void kernel_launch(void* const* d_in, const int* in_sizes, int n_in,
                              void* d_out, int out_size, void* d_ws, size_t ws_size,
                              hipStream_t stream) {
  const float* x   = (const float*)d_in[0];
  const float* h0  = (const float*)d_in[1];
  const float* wih = (const float*)d_in[2];
  const float* whh = (const float*)d_in[3];
  const float* bih = (const float*)d_in[4];
  const float* bhh = (const float*)d_in[5];
  float* out = (float*)d_out;

  char* ws = (char*)d_ws;
  size_t off = 0;
  auto alloc = [&](size_t bytes) -> void* {
    void* p = ws + off;
    off += (bytes + 255) & ~(size_t)255;
    return p;
  };
  u16* xg0   = (u16*)alloc((size_t)TT * BB * G3 * 2);        // 193 MB
  u16* wihb  = (u16*)alloc((size_t)2 * G3 * HH * 2);         // 12.6 MB
  u16* whhb  = (u16*)alloc((size_t)2 * G3 * HH * 2);         // 12.6 MB
  // union: xbf (64 MB, dead after gemm) overlaid by hbuf0/hbuf1 (134.5 MB)
  size_t hbytes = (size_t)2 * NS * SLOT * 2;
  size_t xbytes = (size_t)TT * BB * HH * 2;
  char* un = (char*)alloc(hbytes > xbytes ? hbytes : xbytes);
  u16* xbf   = (u16*)un;
  u16* hbuf0 = (u16*)un;
  u16* hbuf1 = hbuf0 + (size_t)NS * SLOT;
  u16* xg1ring = (u16*)alloc((size_t)RING * BB * G3 * 2);    // 12.6 MB (bf16)
  unsigned* flags0 = (unsigned*)alloc(256 * FSTRIDE * 4);
  unsigned* flags1 = (unsigned*)alloc(256 * FSTRIDE * 4);
  unsigned* flags2 = (unsigned*)alloc(256 * FSTRIDE * 4);

  hipMemsetAsync(flags0, 0, 256 * FSTRIDE * 4, stream);
  hipMemsetAsync(flags1, 0, 256 * FSTRIDE * 4, stream);
  hipMemsetAsync(flags2, 0, 256 * FSTRIDE * 4, stream);
  f32_to_bf16_k<<<2048, 256, 0, stream>>>(x, xbf, TT * BB * HH);
  f32_to_bf16_k<<<512, 256, 0, stream>>>(wih, wihb, 2 * G3 * HH);
  f32_to_bf16_k<<<512, 256, 0, stream>>>(whh, whhb, 2 * G3 * HH);

  gemm_xg_k<<<6144, 256, 0, stream>>>(xbf, wihb, bih, xg0);

  // init h AFTER gemm: hbuf aliases xbf
  init_h_k<<<256, 256, 0, stream>>>(h0, hbuf0, hbuf1);

  gru_scan13_k<<<NBLK, 256, 0, stream>>>(xg0,
                                         whhb, wihb + (size_t)G3 * HH, whhb + (size_t)G3 * HH,
                                         bhh, bih + G3, bhh + G3, h0,
                                         hbuf0, hbuf1, xg1ring, out,
                                         flags0, flags1, flags2);
}

// Round 16
// 5137.924 us; speedup vs baseline: 1.6198x; 1.0493x over previous
//
#include <hip/hip_runtime.h>

typedef unsigned short u16;
typedef unsigned long long u64;
typedef __attribute__((ext_vector_type(8))) short short8;
typedef __attribute__((ext_vector_type(4))) float f32x4;

#define HH 1024
#define BB 64
#define TT 512
#define G3 3072
#define NBLK 192
#define NS 513                 // h time-slots (renamed buffers)
#define SLOT (BB * HH)         // elems per h slot
#define FSTRIDE 32             // flag padding: one 128B line per block
#define RING 32                // xg1 ring depth

__device__ __forceinline__ u16 f2b(float f) {
  unsigned u = __float_as_uint(f);
  unsigned r = (u + 0x7fffu + ((u >> 16) & 1u)) >> 16;
  return (u16)r;
}
__device__ __forceinline__ float b2f(u16 h) {
  return __uint_as_float(((unsigned)h) << 16);
}
__device__ __forceinline__ float ftanh(float x) {
  x = fminf(15.f, fmaxf(-15.f, x));
  float e = __expf(2.f * x);
  return (e - 1.f) / (e + 1.f);
}

__device__ __forceinline__ void st_u32_agent(unsigned* p, unsigned v) {
  __hip_atomic_store(p, v, __ATOMIC_RELAXED, __HIP_MEMORY_SCOPE_AGENT);
}
__device__ __forceinline__ unsigned ld_u32_agent(const unsigned* p) {
  return __hip_atomic_load(p, __ATOMIC_RELAXED, __HIP_MEMORY_SCOPE_AGENT);
}

// ---------------- elementwise converts / init ----------------

__global__ void f32_to_bf16_k(const float* __restrict__ s, u16* __restrict__ d, int n) {
  int stride = gridDim.x * blockDim.x * 4;
  for (int i = (blockIdx.x * blockDim.x + threadIdx.x) * 4; i < n; i += stride) {
    float4 v = *(const float4*)(s + i);
    uint2 p;
    p.x = (unsigned)f2b(v.x) | ((unsigned)f2b(v.y) << 16);
    p.y = (unsigned)f2b(v.z) | ((unsigned)f2b(v.w) << 16);
    *(uint2*)(d + i) = p;
  }
}

__global__ void init_h_k(const float* __restrict__ h0in, u16* __restrict__ hbuf0,
                         u16* __restrict__ hbuf1) {
  int i = blockIdx.x * blockDim.x + threadIdx.x;
  if (i < BB * HH) {
    hbuf0[i] = f2b(h0in[i]);            // slot 0 = H0(0)
    hbuf1[i] = f2b(h0in[BB * HH + i]);  // slot 0 = H1(0)
  }
}

// ---------------- phase A: xg0 = bf16(x @ W_ih0^T + b_ih0) ----------------

__global__ __launch_bounds__(256) void gemm_xg_k(
    const u16* __restrict__ A, const u16* __restrict__ Wt,
    const float* __restrict__ bias, u16* __restrict__ C) {
  const int bm = blockIdx.x / 24;
  const int bn = blockIdx.x % 24;
  const int m0 = bm * 128, n0 = bn * 128;
  __shared__ __align__(16) u16 al[128 * 40];
  __shared__ __align__(16) u16 bl[128 * 40];
  const int tid = threadIdx.x;
  const int w = tid >> 6, l = tid & 63;
  const int wr = w >> 1, wc = w & 1;
  const int c0 = tid, c1 = tid + 256;
  const int r0 = c0 >> 2, s0 = c0 & 3, r1 = c1 >> 2, s1 = c1 & 3;

  const f32x4 fzero = {0.f, 0.f, 0.f, 0.f};
  f32x4 acc[4][4];
#pragma unroll
  for (int i = 0; i < 4; ++i)
#pragma unroll
    for (int j = 0; j < 4; ++j) acc[i][j] = fzero;

  const u16* a0p = A + (size_t)(m0 + r0) * 1024 + s0 * 8;
  const u16* a1p = A + (size_t)(m0 + r1) * 1024 + s1 * 8;
  const u16* b0p = Wt + (size_t)(n0 + r0) * 1024 + s0 * 8;
  const u16* b1p = Wt + (size_t)(n0 + r1) * 1024 + s1 * 8;

  int4 va0 = *(const int4*)(a0p);
  int4 va1 = *(const int4*)(a1p);
  int4 vb0 = *(const int4*)(b0p);
  int4 vb1 = *(const int4*)(b1p);

  for (int kt = 0; kt < 32; ++kt) {
    __syncthreads();
    *(int4*)&al[r0 * 40 + s0 * 8] = va0;
    *(int4*)&al[r1 * 40 + s1 * 8] = va1;
    *(int4*)&bl[r0 * 40 + s0 * 8] = vb0;
    *(int4*)&bl[r1 * 40 + s1 * 8] = vb1;
    __syncthreads();
    if (kt < 31) {
      va0 = *(const int4*)(a0p + (kt + 1) * 32);
      va1 = *(const int4*)(a1p + (kt + 1) * 32);
      vb0 = *(const int4*)(b0p + (kt + 1) * 32);
      vb1 = *(const int4*)(b1p + (kt + 1) * 32);
    }
    short8 af[4], bf[4];
#pragma unroll
    for (int i = 0; i < 4; ++i)
      af[i] = *(const short8*)&al[(wr * 64 + i * 16 + (l & 15)) * 40 + (l >> 4) * 8];
#pragma unroll
    for (int j = 0; j < 4; ++j)
      bf[j] = *(const short8*)&bl[(wc * 64 + j * 16 + (l & 15)) * 40 + (l >> 4) * 8];
#pragma unroll
    for (int i = 0; i < 4; ++i)
#pragma unroll
      for (int j = 0; j < 4; ++j)
        acc[i][j] = __builtin_amdgcn_mfma_f32_16x16x32_bf16(af[i], bf[j], acc[i][j], 0, 0, 0);
  }

#pragma unroll
  for (int i = 0; i < 4; ++i) {
#pragma unroll
    for (int j = 0; j < 4; ++j) {
      int col = n0 + wc * 64 + j * 16 + (l & 15);
      float bv = bias[col];
#pragma unroll
      for (int q = 0; q < 4; ++q) {
        int row = m0 + wr * 64 + i * 16 + (l >> 4) * 4 + q;
        C[(size_t)row * G3 + col] = f2b(acc[i][j][q] + bv);
      }
    }
  }
}

// ---------------- persistent fused scan, v15: IN-ORDER chunked consume ----
// R12 structure (best passing: 8.0 us/step) + overlap of compute with the
// producer-straggler wait, with DETERMINISTIC accumulation: chunks are
// consumed in fixed ascending ks order (identical FP order to R12), stalling
// (re-ballot) only when chunk ks's producer pair (blocks 2ks,2ks+1) hasn't
// posted step t yet. Producer side (stores, block drain, tid0 flag post) is
// R12-identical. Ring waits are single-line (p1 block sub <-> p2 block sub).
//  p0 (blk 0..63):   layer0, t=0..511: inorder(flags0>=t) -> h0[t+1], flags0=t+1
//  p1 (blk 64..127): xg1,    t=1..512: backpressure flags2[sub]>=t-RING,
//      inorder(flags0>=t) -> ring[t&31], flags1[sub]=t
//  p2 (blk 128..191):layer1, t=1..512: ring wait flags1[sub]>=t,
//      inorder(flags2>=t-1) on hbuf1[t-1] -> h1[t], flags2[sub]=t

#define INORDER_GEMM(FLAGS, TGT, AP)                                          \
  {                                                                           \
    unsigned fv = ld_u32_agent(&FLAGS[l * FSTRIDE]);                          \
    u64 ready = __ballot(fv >= (unsigned)(TGT));                              \
    __builtin_amdgcn_fence(__ATOMIC_ACQUIRE, "workgroup");                    \
    _Pragma("unroll")                                                         \
    for (int ks = 0; ks < 32; ++ks) {                                         \
      while (((ready >> (2 * ks)) & 3ull) != 3ull) {                          \
        fv = ld_u32_agent(&FLAGS[l * FSTRIDE]);                               \
        ready = __ballot(fv >= (unsigned)(TGT));                              \
        __builtin_amdgcn_fence(__ATOMIC_ACQUIRE, "workgroup");                \
      }                                                                       \
      short8 a = *(const short8*)((AP) + ks * 32);                            \
      int ke = kb + ks * 32;                                                  \
      short8 b0 = *(const short8*)&wlds[(lrow) * 1024 + (ke ^ sx)];           \
      short8 b1 = *(const short8*)&wlds[(16 + lrow) * 1024 + (ke ^ sx)];      \
      short8 b2 = *(const short8*)&wlds[(32 + lrow) * 1024 + (ke ^ sx)];      \
      acc0 = __builtin_amdgcn_mfma_f32_16x16x32_bf16(a, b0, acc0, 0, 0, 0);   \
      acc1 = __builtin_amdgcn_mfma_f32_16x16x32_bf16(a, b1, acc1, 0, 0, 0);   \
      acc2 = __builtin_amdgcn_mfma_f32_16x16x32_bf16(a, b2, acc2, 0, 0, 0);   \
    }                                                                         \
  }

__global__ __launch_bounds__(256, 1) void gru_scan15_k(
    const u16* __restrict__ xg0,
    const u16* __restrict__ whh0, const u16* __restrict__ wih1,
    const u16* __restrict__ whh1,
    const float* __restrict__ bhh0, const float* __restrict__ bih1,
    const float* __restrict__ bhh1,
    const float* __restrict__ h0in,
    u16* __restrict__ hbuf0, u16* __restrict__ hbuf1,
    u16* __restrict__ xg1ring, float* __restrict__ out,
    unsigned* __restrict__ flags0, unsigned* __restrict__ flags1,
    unsigned* __restrict__ flags2) {
  const int blk = blockIdx.x;
  const int grp = blk >> 6;          // 0,1,2
  const int sub = blk & 63;
  const int tid = threadIdx.x;
  const int w = tid >> 6, l = tid & 63;
  const int lrow = l & 15;
  const int kb = (l >> 4) * 8;
  const int myrow0 = w * 16 + (l >> 4) * 4;
  const size_t arow = (size_t)(w * 16 + lrow) * HH + kb;
  const f32x4 fzero = {0.f, 0.f, 0.f, 0.f};

  __shared__ __align__(16) u16 wlds[48 * 1024];
  {
    const u16* Wsrc = (grp == 0) ? whh0 : (grp == 1) ? wih1 : whh1;
    for (int i = tid; i < 6144; i += 256) {
      int r = i >> 7;
      int c = i & 127;
      int g = r >> 4;
      int wrow = g * HH + sub * 16 + (r & 15);
      int4 v = *(const int4*)(Wsrc + (size_t)wrow * 1024 + c * 8);
      int idx = r * 1024 + ((c * 8) ^ ((r & 7) << 3));
      *(int4*)&wlds[idx] = v;
    }
  }
  __syncthreads();
  // one-time cross-replay staleness guard
  __builtin_amdgcn_fence(__ATOMIC_ACQUIRE, "agent");

  const int j = sub * 16 + lrow;
  const int sx = (lrow & 7) << 3;

  if (grp == 0) {
    const float bhr = bhh0[j], bhz = bhh0[HH + j], bhn = bhh0[2 * HH + j];
    float hreg[4];
#pragma unroll
    for (int q = 0; q < 4; ++q) hreg[q] = h0in[(myrow0 + q) * HH + j];

    for (int t = 0; t < TT; ++t) {
      // xg0 prefetch (cached; completes under the consume)
      u16 xrv[4], xzv[4], xnv[4];
      const u16* xp = xg0 + (size_t)t * BB * G3;
#pragma unroll
      for (int q = 0; q < 4; ++q) {
        const u16* rp = xp + (size_t)(myrow0 + q) * G3;
        xrv[q] = rp[j]; xzv[q] = rp[HH + j]; xnv[q] = rp[2 * HH + j];
      }

      const u16* Ap = hbuf0 + (size_t)t * SLOT + arow;
      f32x4 acc0 = fzero, acc1 = fzero, acc2 = fzero;
      if (t == 0) {
#pragma unroll
        for (int ks = 0; ks < 32; ++ks) {
          short8 a = *(const short8*)(Ap + ks * 32);
          int ke = kb + ks * 32;
          short8 b0 = *(const short8*)&wlds[(lrow) * 1024 + (ke ^ sx)];
          short8 b1 = *(const short8*)&wlds[(16 + lrow) * 1024 + (ke ^ sx)];
          short8 b2 = *(const short8*)&wlds[(32 + lrow) * 1024 + (ke ^ sx)];
          acc0 = __builtin_amdgcn_mfma_f32_16x16x32_bf16(a, b0, acc0, 0, 0, 0);
          acc1 = __builtin_amdgcn_mfma_f32_16x16x32_bf16(a, b1, acc1, 0, 0, 0);
          acc2 = __builtin_amdgcn_mfma_f32_16x16x32_bf16(a, b2, acc2, 0, 0, 0);
        }
      } else {
        INORDER_GEMM(flags0, t, Ap)
      }

      u16* hbn = hbuf0 + (size_t)(t + 1) * SLOT;
#pragma unroll
      for (int q = 0; q < 4; ++q) {
        float rr = acc0[q] + bhr + b2f(xrv[q]);
        float zz = acc1[q] + bhz + b2f(xzv[q]);
        float nn = acc2[q] + bhn;
        float r = 1.f / (1.f + __expf(-rr));
        float z = 1.f / (1.f + __expf(-zz));
        float n = ftanh(b2f(xnv[q]) + r * nn);
        float hv = (1.f - z) * n + z * hreg[q];
        hreg[q] = hv;
        int hb = (int)f2b(hv);
        int nb = __shfl_xor(hb, 1);
        if ((l & 1) == 0) {
          unsigned pk = (unsigned)(u16)hb | (((unsigned)(u16)nb) << 16);
          st_u32_agent((unsigned*)(hbn + (size_t)(myrow0 + q) * HH + j), pk);
        }
      }

      __syncthreads();  // block-wide drain of sc1 stores
      if (tid == 0) {
        __builtin_amdgcn_fence(__ATOMIC_RELEASE, "workgroup");
        st_u32_agent(&flags0[sub * FSTRIDE], (unsigned)(t + 1));
      }
    }
#pragma unroll
    for (int q = 0; q < 4; ++q) out[(size_t)(myrow0 + q) * HH + j] = hreg[q];

  } else if (grp == 1) {
    const float bir = bih1[j], biz = bih1[HH + j], bin = bih1[2 * HH + j];

    for (int t = 1; t <= TT; ++t) {
      // ring back-pressure: single line (consumer is exactly p2 block sub)
      for (;;) {
        unsigned f2 = ld_u32_agent(&flags2[sub * FSTRIDE]);
        if ((int)f2 >= t - RING) break;
      }

      const u16* Ap = hbuf0 + (size_t)t * SLOT + arow;
      f32x4 acc0 = fzero, acc1 = fzero, acc2 = fzero;
      INORDER_GEMM(flags0, t, Ap)

      u16* ox = xg1ring + (size_t)(t & (RING - 1)) * (BB * G3);
#pragma unroll
      for (int q = 0; q < 4; ++q) {
        int row = myrow0 + q;
        int a0v = (int)f2b(acc0[q] + bir); int a0n = __shfl_xor(a0v, 1);
        int a1v = (int)f2b(acc1[q] + biz); int a1n = __shfl_xor(a1v, 1);
        int a2v = (int)f2b(acc2[q] + bin); int a2n = __shfl_xor(a2v, 1);
        if ((l & 1) == 0) {
          st_u32_agent((unsigned*)(ox + (size_t)row * G3 + j),
                       (unsigned)(u16)a0v | (((unsigned)(u16)a0n) << 16));
          st_u32_agent((unsigned*)(ox + (size_t)row * G3 + HH + j),
                       (unsigned)(u16)a1v | (((unsigned)(u16)a1n) << 16));
          st_u32_agent((unsigned*)(ox + (size_t)row * G3 + 2 * HH + j),
                       (unsigned)(u16)a2v | (((unsigned)(u16)a2n) << 16));
        }
      }

      __syncthreads();
      if (tid == 0) {
        __builtin_amdgcn_fence(__ATOMIC_RELEASE, "workgroup");
        st_u32_agent(&flags1[sub * FSTRIDE], (unsigned)t);
      }
    }

  } else {
    const float bhr = bhh1[j], bhz = bhh1[HH + j], bhn = bhh1[2 * HH + j];
    float hreg[4];
#pragma unroll
    for (int q = 0; q < 4; ++q) hreg[q] = h0in[BB * HH + (myrow0 + q) * HH + j];
    const int jpair = j & ~1;
    const int sel = (j & 1) * 16;

    for (int t = 1; t <= TT; ++t) {
      // ring producer wait: single line (p1 block sub feeds exactly this block)
      for (;;) {
        unsigned f1 = ld_u32_agent(&flags1[sub * FSTRIDE]);
        if (f1 >= (unsigned)t) break;
      }
      __builtin_amdgcn_fence(__ATOMIC_ACQUIRE, "workgroup");

      // ring loads fly during the consume
      const u16* ox = xg1ring + (size_t)(t & (RING - 1)) * (BB * G3);
      unsigned pr[4], pz[4], pn[4];
#pragma unroll
      for (int q = 0; q < 4; ++q) {
        const u16* rp = ox + (size_t)(myrow0 + q) * G3;
        pr[q] = ld_u32_agent((const unsigned*)(rp + jpair));
        pz[q] = ld_u32_agent((const unsigned*)(rp + HH + jpair));
        pn[q] = ld_u32_agent((const unsigned*)(rp + 2 * HH + jpair));
      }

      const u16* Ap = hbuf1 + (size_t)(t - 1) * SLOT + arow;
      f32x4 acc0 = fzero, acc1 = fzero, acc2 = fzero;
      INORDER_GEMM(flags2, t - 1, Ap)

      u16* hbn = hbuf1 + (size_t)t * SLOT;
#pragma unroll
      for (int q = 0; q < 4; ++q) {
        float rr = acc0[q] + bhr + b2f((u16)(pr[q] >> sel));
        float zz = acc1[q] + bhz + b2f((u16)(pz[q] >> sel));
        float nn = acc2[q] + bhn;
        float r = 1.f / (1.f + __expf(-rr));
        float z = 1.f / (1.f + __expf(-zz));
        float n = ftanh(b2f((u16)(pn[q] >> sel)) + r * nn);
        float hv = (1.f - z) * n + z * hreg[q];
        hreg[q] = hv;
        int hb = (int)f2b(hv);
        int nb = __shfl_xor(hb, 1);
        if ((l & 1) == 0) {
          unsigned pk = (unsigned)(u16)hb | (((unsigned)(u16)nb) << 16);
          st_u32_agent((unsigned*)(hbn + (size_t)(myrow0 + q) * HH + j), pk);
        }
      }

      __syncthreads();
      if (tid == 0) {
        __builtin_amdgcn_fence(__ATOMIC_RELEASE, "workgroup");
        st_u32_agent(&flags2[sub * FSTRIDE], (unsigned)t);
      }
    }
#pragma unroll
    for (int q = 0; q < 4; ++q) out[BB * HH + (size_t)(myrow0 + q) * HH + j] = hreg[q];
  }
}

// ---------------- host ----------------

extern "C" void kernel_launch(void* const* d_in, const int* in_sizes, int n_in,
                              void* d_out, int out_size, void* d_ws, size_t ws_size,
                              hipStream_t stream) {
  const float* x   = (const float*)d_in[0];
  const float* h0  = (const float*)d_in[1];
  const float* wih = (const float*)d_in[2];
  const float* whh = (const float*)d_in[3];
  const float* bih = (const float*)d_in[4];
  const float* bhh = (const float*)d_in[5];
  float* out = (float*)d_out;

  char* ws = (char*)d_ws;
  size_t off = 0;
  auto alloc = [&](size_t bytes) -> void* {
    void* p = ws + off;
    off += (bytes + 255) & ~(size_t)255;
    return p;
  };
  u16* xg0   = (u16*)alloc((size_t)TT * BB * G3 * 2);        // 193 MB
  u16* wihb  = (u16*)alloc((size_t)2 * G3 * HH * 2);         // 12.6 MB
  u16* whhb  = (u16*)alloc((size_t)2 * G3 * HH * 2);         // 12.6 MB
  // union: xbf (64 MB, dead after gemm) overlaid by hbuf0/hbuf1 (134.5 MB)
  size_t hbytes = (size_t)2 * NS * SLOT * 2;
  size_t xbytes = (size_t)TT * BB * HH * 2;
  char* un = (char*)alloc(hbytes > xbytes ? hbytes : xbytes);
  u16* xbf   = (u16*)un;
  u16* hbuf0 = (u16*)un;
  u16* hbuf1 = hbuf0 + (size_t)NS * SLOT;
  u16* xg1ring = (u16*)alloc((size_t)RING * BB * G3 * 2);    // 12.6 MB (bf16)
  unsigned* flags0 = (unsigned*)alloc(64 * FSTRIDE * 4);
  unsigned* flags1 = (unsigned*)alloc(64 * FSTRIDE * 4);
  unsigned* flags2 = (unsigned*)alloc(64 * FSTRIDE * 4);

  hipMemsetAsync(flags0, 0, 64 * FSTRIDE * 4, stream);
  hipMemsetAsync(flags1, 0, 64 * FSTRIDE * 4, stream);
  hipMemsetAsync(flags2, 0, 64 * FSTRIDE * 4, stream);
  f32_to_bf16_k<<<2048, 256, 0, stream>>>(x, xbf, TT * BB * HH);
  f32_to_bf16_k<<<512, 256, 0, stream>>>(wih, wihb, 2 * G3 * HH);
  f32_to_bf16_k<<<512, 256, 0, stream>>>(whh, whhb, 2 * G3 * HH);

  gemm_xg_k<<<6144, 256, 0, stream>>>(xbf, wihb, bih, xg0);

  // init h AFTER gemm: hbuf aliases xbf
  init_h_k<<<256, 256, 0, stream>>>(h0, hbuf0, hbuf1);

  gru_scan15_k<<<NBLK, 256, 0, stream>>>(xg0,
                                         whhb, wihb + (size_t)G3 * HH, whhb + (size_t)G3 * HH,
                                         bhh, bih + G3, bhh + G3, h0,
                                         hbuf0, hbuf1, xg1ring, out,
                                         flags0, flags1, flags2);
}

// Round 17
// 4416.128 us; speedup vs baseline: 1.8845x; 1.1634x over previous
//
#include <hip/hip_runtime.h>

typedef unsigned short u16;
typedef unsigned long long u64;
typedef __attribute__((ext_vector_type(8))) short short8;
typedef __attribute__((ext_vector_type(4))) float f32x4;

#define HH 1024
#define BB 64
#define TT 512
#define G3 3072
#define NBLK 192
#define NS 513                 // h time-slots (renamed buffers)
#define SLOT (BB * HH)         // elems per h slot
#define FSTRIDE 32             // flag padding: one 128B line per block
#define RING 8                 // xg1 ring depth

__device__ __forceinline__ u16 f2b(float f) {
  unsigned u = __float_as_uint(f);
  unsigned r = (u + 0x7fffu + ((u >> 16) & 1u)) >> 16;
  return (u16)r;
}
__device__ __forceinline__ float b2f(u16 h) {
  return __uint_as_float(((unsigned)h) << 16);
}
__device__ __forceinline__ float ftanh(float x) {
  x = fminf(15.f, fmaxf(-15.f, x));
  float e = __expf(2.f * x);
  return (e - 1.f) / (e + 1.f);
}

__device__ __forceinline__ void st_u32_agent(unsigned* p, unsigned v) {
  __hip_atomic_store(p, v, __ATOMIC_RELAXED, __HIP_MEMORY_SCOPE_AGENT);
}
__device__ __forceinline__ unsigned ld_u32_agent(const unsigned* p) {
  return __hip_atomic_load(p, __ATOMIC_RELAXED, __HIP_MEMORY_SCOPE_AGENT);
}

// ---------------- elementwise converts / init ----------------

__global__ void f32_to_bf16_k(const float* __restrict__ s, u16* __restrict__ d, int n) {
  int stride = gridDim.x * blockDim.x * 4;
  for (int i = (blockIdx.x * blockDim.x + threadIdx.x) * 4; i < n; i += stride) {
    float4 v = *(const float4*)(s + i);
    uint2 p;
    p.x = (unsigned)f2b(v.x) | ((unsigned)f2b(v.y) << 16);
    p.y = (unsigned)f2b(v.z) | ((unsigned)f2b(v.w) << 16);
    *(uint2*)(d + i) = p;
  }
}

__global__ void init_h_k(const float* __restrict__ h0in, u16* __restrict__ hbuf0,
                         u16* __restrict__ hbuf1) {
  int i = blockIdx.x * blockDim.x + threadIdx.x;
  if (i < BB * HH) {
    hbuf0[i] = f2b(h0in[i]);            // slot 0 = H0(0)
    hbuf1[i] = f2b(h0in[BB * HH + i]);  // slot 0 = H1(0)
  }
}

// ---------------- phase A: xg0 = bf16(x @ W_ih0^T + b_ih0) ----------------

__global__ __launch_bounds__(256) void gemm_xg_k(
    const u16* __restrict__ A, const u16* __restrict__ Wt,
    const float* __restrict__ bias, u16* __restrict__ C) {
  const int bm = blockIdx.x / 24;
  const int bn = blockIdx.x % 24;
  const int m0 = bm * 128, n0 = bn * 128;
  __shared__ __align__(16) u16 al[128 * 40];
  __shared__ __align__(16) u16 bl[128 * 40];
  const int tid = threadIdx.x;
  const int w = tid >> 6, l = tid & 63;
  const int wr = w >> 1, wc = w & 1;
  const int c0 = tid, c1 = tid + 256;
  const int r0 = c0 >> 2, s0 = c0 & 3, r1 = c1 >> 2, s1 = c1 & 3;

  const f32x4 fzero = {0.f, 0.f, 0.f, 0.f};
  f32x4 acc[4][4];
#pragma unroll
  for (int i = 0; i < 4; ++i)
#pragma unroll
    for (int j = 0; j < 4; ++j) acc[i][j] = fzero;

  const u16* a0p = A + (size_t)(m0 + r0) * 1024 + s0 * 8;
  const u16* a1p = A + (size_t)(m0 + r1) * 1024 + s1 * 8;
  const u16* b0p = Wt + (size_t)(n0 + r0) * 1024 + s0 * 8;
  const u16* b1p = Wt + (size_t)(n0 + r1) * 1024 + s1 * 8;

  int4 va0 = *(const int4*)(a0p);
  int4 va1 = *(const int4*)(a1p);
  int4 vb0 = *(const int4*)(b0p);
  int4 vb1 = *(const int4*)(b1p);

  for (int kt = 0; kt < 32; ++kt) {
    __syncthreads();
    *(int4*)&al[r0 * 40 + s0 * 8] = va0;
    *(int4*)&al[r1 * 40 + s1 * 8] = va1;
    *(int4*)&bl[r0 * 40 + s0 * 8] = vb0;
    *(int4*)&bl[r1 * 40 + s1 * 8] = vb1;
    __syncthreads();
    if (kt < 31) {
      va0 = *(const int4*)(a0p + (kt + 1) * 32);
      va1 = *(const int4*)(a1p + (kt + 1) * 32);
      vb0 = *(const int4*)(b0p + (kt + 1) * 32);
      vb1 = *(const int4*)(b1p + (kt + 1) * 32);
    }
    short8 af[4], bf[4];
#pragma unroll
    for (int i = 0; i < 4; ++i)
      af[i] = *(const short8*)&al[(wr * 64 + i * 16 + (l & 15)) * 40 + (l >> 4) * 8];
#pragma unroll
    for (int j = 0; j < 4; ++j)
      bf[j] = *(const short8*)&bl[(wc * 64 + j * 16 + (l & 15)) * 40 + (l >> 4) * 8];
#pragma unroll
    for (int i = 0; i < 4; ++i)
#pragma unroll
      for (int j = 0; j < 4; ++j)
        acc[i][j] = __builtin_amdgcn_mfma_f32_16x16x32_bf16(af[i], bf[j], acc[i][j], 0, 0, 0);
  }

#pragma unroll
  for (int i = 0; i < 4; ++i) {
#pragma unroll
    for (int j = 0; j < 4; ++j) {
      int col = n0 + wc * 64 + j * 16 + (l & 15);
      float bv = bias[col];
#pragma unroll
      for (int q = 0; q < 4; ++q) {
        int row = m0 + wr * 64 + i * 16 + (l >> 4) * 4 + q;
        C[(size_t)row * G3 + col] = f2b(acc[i][j][q] + bv);
      }
    }
  }
}

// ---------------- persistent fused scan (R12 structure, best) ----------------
// 3 decoupled 1-GEMM groups; renamed h slots (sc1 writes -> LLC, normal
// cached reads, no in-loop fences); padded per-block flags; wave0-only poll;
// packed-bf16 xg1 ring; busy-poll detect.
//  p0 (blk 0..63):   layer0 step t, t=0..511. flags0.
//  p1 (blk 64..127): xg1 producer, t=1..512. flags0 + ring backpressure.
//  p2 (blk 128..191):layer1 step,  t=1..512. flags1 + own flags2.

__global__ __launch_bounds__(256, 1) void gru_scan11_k(
    const u16* __restrict__ xg0,
    const u16* __restrict__ whh0, const u16* __restrict__ wih1,
    const u16* __restrict__ whh1,
    const float* __restrict__ bhh0, const float* __restrict__ bih1,
    const float* __restrict__ bhh1,
    const float* __restrict__ h0in,
    u16* __restrict__ hbuf0, u16* __restrict__ hbuf1,
    u16* __restrict__ xg1ring, float* __restrict__ out,
    unsigned* __restrict__ flags) {
  const int blk = blockIdx.x;
  const int grp = blk >> 6;          // 0,1,2
  const int sub = blk & 63;
  const int tid = threadIdx.x;
  const int w = tid >> 6, l = tid & 63;
  const int lrow = l & 15;
  const int kb = (l >> 4) * 8;
  const int myrow0 = w * 16 + (l >> 4) * 4;
  const size_t arow = (size_t)(w * 16 + lrow) * HH + kb;
  const f32x4 fzero = {0.f, 0.f, 0.f, 0.f};

  __shared__ __align__(16) u16 wlds[48 * 1024];
  {
    const u16* Wsrc = (grp == 0) ? whh0 : (grp == 1) ? wih1 : whh1;
    for (int i = tid; i < 6144; i += 256) {
      int r = i >> 7;
      int c = i & 127;
      int g = r >> 4;
      int wrow = g * HH + sub * 16 + (r & 15);
      int4 v = *(const int4*)(Wsrc + (size_t)wrow * 1024 + c * 8);
      int idx = r * 1024 + ((c * 8) ^ ((r & 7) << 3));
      *(int4*)&wlds[idx] = v;
    }
  }
  __syncthreads();
  // one-time cross-replay staleness guard (renamed slots reused across graph
  // replays; W already safe in LDS)
  __builtin_amdgcn_fence(__ATOMIC_ACQUIRE, "agent");

  const int j = sub * 16 + lrow;
  const int sx = (lrow & 7) << 3;

  if (grp == 0) {
    const float bhr = bhh0[j], bhz = bhh0[HH + j], bhn = bhh0[2 * HH + j];
    float hreg[4];
#pragma unroll
    for (int q = 0; q < 4; ++q) hreg[q] = h0in[(myrow0 + q) * HH + j];

    for (int t = 0; t < TT; ++t) {
      // hoist xg0 loads: address-known, latency hides under the poll
      u16 xrv[4], xzv[4], xnv[4];
      const u16* xp = xg0 + (size_t)t * BB * G3;
#pragma unroll
      for (int q = 0; q < 4; ++q) {
        const u16* rp = xp + (size_t)(myrow0 + q) * G3;
        xrv[q] = rp[j]; xzv[q] = rp[HH + j]; xnv[q] = rp[2 * HH + j];
      }
      if (t > 0) {
        if (tid < 64) {
          for (;;) {
            unsigned a0 = ld_u32_agent(&flags[l * FSTRIDE]);
            if (__all(a0 >= (unsigned)t)) break;
          }
        }
        __syncthreads();
        __builtin_amdgcn_fence(__ATOMIC_ACQUIRE, "workgroup");
      }

      const u16* Ap = hbuf0 + (size_t)t * SLOT + arow;
      short8 ar[32];
#pragma unroll
      for (int ks = 0; ks < 32; ++ks) ar[ks] = *(const short8*)(Ap + ks * 32);

      f32x4 acc0 = fzero, acc1 = fzero, acc2 = fzero;
#pragma unroll
      for (int ks = 0; ks < 32; ++ks) {
        int ke = kb + ks * 32;
        short8 b0 = *(const short8*)&wlds[(lrow) * 1024 + (ke ^ sx)];
        short8 b1 = *(const short8*)&wlds[(16 + lrow) * 1024 + (ke ^ sx)];
        short8 b2 = *(const short8*)&wlds[(32 + lrow) * 1024 + (ke ^ sx)];
        acc0 = __builtin_amdgcn_mfma_f32_16x16x32_bf16(ar[ks], b0, acc0, 0, 0, 0);
        acc1 = __builtin_amdgcn_mfma_f32_16x16x32_bf16(ar[ks], b1, acc1, 0, 0, 0);
        acc2 = __builtin_amdgcn_mfma_f32_16x16x32_bf16(ar[ks], b2, acc2, 0, 0, 0);
      }

      u16* hbn = hbuf0 + (size_t)(t + 1) * SLOT;
#pragma unroll
      for (int q = 0; q < 4; ++q) {
        float rr = acc0[q] + bhr + b2f(xrv[q]);
        float zz = acc1[q] + bhz + b2f(xzv[q]);
        float nn = acc2[q] + bhn;
        float r = 1.f / (1.f + __expf(-rr));
        float z = 1.f / (1.f + __expf(-zz));
        float n = ftanh(b2f(xnv[q]) + r * nn);
        float hv = (1.f - z) * n + z * hreg[q];
        hreg[q] = hv;
        int hb = (int)f2b(hv);
        int nb = __shfl_xor(hb, 1);
        if ((l & 1) == 0) {
          unsigned pk = (unsigned)(u16)hb | (((unsigned)(u16)nb) << 16);
          st_u32_agent((unsigned*)(hbn + (size_t)(myrow0 + q) * HH + j), pk);
        }
      }

      __syncthreads();  // drain sc1 stores
      if (tid == 0) {
        __builtin_amdgcn_fence(__ATOMIC_RELEASE, "workgroup");
        st_u32_agent(&flags[blk * FSTRIDE], (unsigned)(t + 1));
      }
    }
#pragma unroll
    for (int q = 0; q < 4; ++q) out[(size_t)(myrow0 + q) * HH + j] = hreg[q];

  } else if (grp == 1) {
    const float bir = bih1[j], biz = bih1[HH + j], bin = bih1[2 * HH + j];

    for (int t = 1; t <= TT; ++t) {
      if (tid < 64) {
        for (;;) {
          unsigned a0 = ld_u32_agent(&flags[l * FSTRIDE]);
          unsigned a2 = ld_u32_agent(&flags[(128 + l) * FSTRIDE]);
          int ok = (a0 >= (unsigned)t) && ((int)a2 >= t - RING);
          if (__all(ok)) break;
        }
      }
      __syncthreads();
      __builtin_amdgcn_fence(__ATOMIC_ACQUIRE, "workgroup");

      const u16* Ap = hbuf0 + (size_t)t * SLOT + arow;
      short8 ar[32];
#pragma unroll
      for (int ks = 0; ks < 32; ++ks) ar[ks] = *(const short8*)(Ap + ks * 32);

      f32x4 acc0 = fzero, acc1 = fzero, acc2 = fzero;
#pragma unroll
      for (int ks = 0; ks < 32; ++ks) {
        int ke = kb + ks * 32;
        short8 b0 = *(const short8*)&wlds[(lrow) * 1024 + (ke ^ sx)];
        short8 b1 = *(const short8*)&wlds[(16 + lrow) * 1024 + (ke ^ sx)];
        short8 b2 = *(const short8*)&wlds[(32 + lrow) * 1024 + (ke ^ sx)];
        acc0 = __builtin_amdgcn_mfma_f32_16x16x32_bf16(ar[ks], b0, acc0, 0, 0, 0);
        acc1 = __builtin_amdgcn_mfma_f32_16x16x32_bf16(ar[ks], b1, acc1, 0, 0, 0);
        acc2 = __builtin_amdgcn_mfma_f32_16x16x32_bf16(ar[ks], b2, acc2, 0, 0, 0);
      }

      // packed bf16 ring write: even lane stores {col j (lo), col j+1 (hi)}
      u16* ox = xg1ring + (size_t)(t & (RING - 1)) * (BB * G3);
#pragma unroll
      for (int q = 0; q < 4; ++q) {
        int row = myrow0 + q;
        int a0v = (int)f2b(acc0[q] + bir); int a0n = __shfl_xor(a0v, 1);
        int a1v = (int)f2b(acc1[q] + biz); int a1n = __shfl_xor(a1v, 1);
        int a2v = (int)f2b(acc2[q] + bin); int a2n = __shfl_xor(a2v, 1);
        if ((l & 1) == 0) {
          st_u32_agent((unsigned*)(ox + (size_t)row * G3 + j),
                       (unsigned)(u16)a0v | (((unsigned)(u16)a0n) << 16));
          st_u32_agent((unsigned*)(ox + (size_t)row * G3 + HH + j),
                       (unsigned)(u16)a1v | (((unsigned)(u16)a1n) << 16));
          st_u32_agent((unsigned*)(ox + (size_t)row * G3 + 2 * HH + j),
                       (unsigned)(u16)a2v | (((unsigned)(u16)a2n) << 16));
        }
      }

      __syncthreads();
      if (tid == 0) {
        __builtin_amdgcn_fence(__ATOMIC_RELEASE, "workgroup");
        st_u32_agent(&flags[blk * FSTRIDE], (unsigned)t);
      }
    }

  } else {
    const float bhr = bhh1[j], bhz = bhh1[HH + j], bhn = bhh1[2 * HH + j];
    float hreg[4];
#pragma unroll
    for (int q = 0; q < 4; ++q) hreg[q] = h0in[BB * HH + (myrow0 + q) * HH + j];
    const int jpair = j & ~1;           // even base col of this lane's pair
    const int sel = (j & 1) * 16;       // extract shift

    for (int t = 1; t <= TT; ++t) {
      if (tid < 64) {
        for (;;) {
          unsigned a1 = ld_u32_agent(&flags[(64 + l) * FSTRIDE]);
          unsigned a2 = ld_u32_agent(&flags[(128 + l) * FSTRIDE]);
          int ok = (a1 >= (unsigned)t) && (a2 >= (unsigned)(t - 1));
          if (__all(ok)) break;
        }
      }
      __syncthreads();
      __builtin_amdgcn_fence(__ATOMIC_ACQUIRE, "workgroup");

      // batch: A (cached, renamed) + xg1 ring (sc1 packed bf16)
      const u16* Ap = hbuf1 + (size_t)(t - 1) * SLOT + arow;
      short8 ar[32];
#pragma unroll
      for (int ks = 0; ks < 32; ++ks) ar[ks] = *(const short8*)(Ap + ks * 32);
      const u16* ox = xg1ring + (size_t)(t & (RING - 1)) * (BB * G3);
      float xg1v[3][4];
#pragma unroll
      for (int q = 0; q < 4; ++q) {
        const u16* rp = ox + (size_t)(myrow0 + q) * G3;
        unsigned pr = ld_u32_agent((const unsigned*)(rp + jpair));
        unsigned pz = ld_u32_agent((const unsigned*)(rp + HH + jpair));
        unsigned pn = ld_u32_agent((const unsigned*)(rp + 2 * HH + jpair));
        xg1v[0][q] = b2f((u16)(pr >> sel));
        xg1v[1][q] = b2f((u16)(pz >> sel));
        xg1v[2][q] = b2f((u16)(pn >> sel));
      }

      f32x4 acc0 = fzero, acc1 = fzero, acc2 = fzero;
#pragma unroll
      for (int ks = 0; ks < 32; ++ks) {
        int ke = kb + ks * 32;
        short8 b0 = *(const short8*)&wlds[(lrow) * 1024 + (ke ^ sx)];
        short8 b1 = *(const short8*)&wlds[(16 + lrow) * 1024 + (ke ^ sx)];
        short8 b2 = *(const short8*)&wlds[(32 + lrow) * 1024 + (ke ^ sx)];
        acc0 = __builtin_amdgcn_mfma_f32_16x16x32_bf16(ar[ks], b0, acc0, 0, 0, 0);
        acc1 = __builtin_amdgcn_mfma_f32_16x16x32_bf16(ar[ks], b1, acc1, 0, 0, 0);
        acc2 = __builtin_amdgcn_mfma_f32_16x16x32_bf16(ar[ks], b2, acc2, 0, 0, 0);
      }

      u16* hbn = hbuf1 + (size_t)t * SLOT;
#pragma unroll
      for (int q = 0; q < 4; ++q) {
        float rr = acc0[q] + bhr + xg1v[0][q];
        float zz = acc1[q] + bhz + xg1v[1][q];
        float nn = acc2[q] + bhn;
        float r = 1.f / (1.f + __expf(-rr));
        float z = 1.f / (1.f + __expf(-zz));
        float n = ftanh(xg1v[2][q] + r * nn);
        float hv = (1.f - z) * n + z * hreg[q];
        hreg[q] = hv;
        int hb = (int)f2b(hv);
        int nb = __shfl_xor(hb, 1);
        if ((l & 1) == 0) {
          unsigned pk = (unsigned)(u16)hb | (((unsigned)(u16)nb) << 16);
          st_u32_agent((unsigned*)(hbn + (size_t)(myrow0 + q) * HH + j), pk);
        }
      }

      __syncthreads();
      if (tid == 0) {
        __builtin_amdgcn_fence(__ATOMIC_RELEASE, "workgroup");
        st_u32_agent(&flags[blk * FSTRIDE], (unsigned)t);
      }
    }
#pragma unroll
    for (int q = 0; q < 4; ++q) out[BB * HH + (size_t)(myrow0 + q) * HH + j] = hreg[q];
  }
}

// ---------------- host ----------------

extern "C" void kernel_launch(void* const* d_in, const int* in_sizes, int n_in,
                              void* d_out, int out_size, void* d_ws, size_t ws_size,
                              hipStream_t stream) {
  const float* x   = (const float*)d_in[0];
  const float* h0  = (const float*)d_in[1];
  const float* wih = (const float*)d_in[2];
  const float* whh = (const float*)d_in[3];
  const float* bih = (const float*)d_in[4];
  const float* bhh = (const float*)d_in[5];
  float* out = (float*)d_out;

  char* ws = (char*)d_ws;
  size_t off = 0;
  auto alloc = [&](size_t bytes) -> void* {
    void* p = ws + off;
    off += (bytes + 255) & ~(size_t)255;
    return p;
  };
  u16* xg0   = (u16*)alloc((size_t)TT * BB * G3 * 2);        // 193 MB
  u16* wihb  = (u16*)alloc((size_t)2 * G3 * HH * 2);         // 12.6 MB
  u16* whhb  = (u16*)alloc((size_t)2 * G3 * HH * 2);         // 12.6 MB
  // union: xbf (64 MB, dead after gemm) overlaid by hbuf0/hbuf1 (134.5 MB)
  size_t hbytes = (size_t)2 * NS * SLOT * 2;
  size_t xbytes = (size_t)TT * BB * HH * 2;
  char* un = (char*)alloc(hbytes > xbytes ? hbytes : xbytes);
  u16* xbf   = (u16*)un;
  u16* hbuf0 = (u16*)un;
  u16* hbuf1 = hbuf0 + (size_t)NS * SLOT;
  u16* xg1ring = (u16*)alloc((size_t)RING * BB * G3 * 2);    // 3.1 MB (bf16)
  unsigned* flags = (unsigned*)alloc(NBLK * FSTRIDE * 4);

  hipMemsetAsync(flags, 0, NBLK * FSTRIDE * 4, stream);
  f32_to_bf16_k<<<2048, 256, 0, stream>>>(x, xbf, TT * BB * HH);
  f32_to_bf16_k<<<512, 256, 0, stream>>>(wih, wihb, 2 * G3 * HH);
  f32_to_bf16_k<<<512, 256, 0, stream>>>(whh, whhb, 2 * G3 * HH);

  gemm_xg_k<<<6144, 256, 0, stream>>>(xbf, wihb, bih, xg0);

  // init h AFTER gemm: hbuf aliases xbf
  init_h_k<<<256, 256, 0, stream>>>(h0, hbuf0, hbuf1);

  gru_scan11_k<<<NBLK, 256, 0, stream>>>(xg0,
                                         whhb, wihb + (size_t)G3 * HH, whhb + (size_t)G3 * HH,
                                         bhh, bih + G3, bhh + G3, h0,
                                         hbuf0, hbuf1, xg1ring, out, flags);
}